// Round 4
// baseline (156.737 us; speedup 1.0000x reference)
//
#include <hip/hip_runtime.h>
#include <math.h>

#define NB 4
#define SEQ 1024
#define DM 1024
#define NH 16
#define HS 64

typedef __attribute__((ext_vector_type(8))) short short8;
typedef __attribute__((ext_vector_type(4))) short short4v;
typedef __attribute__((ext_vector_type(4))) float floatx4;
typedef __attribute__((ext_vector_type(16))) float floatx16;

#define MFMA(a, b, c) __builtin_amdgcn_mfma_f32_16x16x32_bf16((a), (b), (c), 0, 0, 0)
#define MFMA32(a, b, c) __builtin_amdgcn_mfma_f32_32x32x16_bf16((a), (b), (c), 0, 0, 0)

static __device__ __forceinline__ unsigned short f2bf(float f) {
  unsigned int u = __float_as_uint(f);
  u += 0x7FFFu + ((u >> 16) & 1u);   // RNE (used in weight prep)
  return (unsigned short)(u >> 16);
}
// Cheap biased-RN bf16 (1 add + hi16). <=0.5 ulp vs RNE; finite inputs only.
static __device__ __forceinline__ unsigned short f2bf_fast(float f) {
  return (unsigned short)((__float_as_uint(f) + 0x8000u) >> 16);
}
// v_cvt_pk_bf16_f32: dst.lo16 = bf16(lo), dst.hi16 = bf16(hi). No builtin (m240).
static __device__ __forceinline__ unsigned cvtpk(float lo, float hi) {
  unsigned r;
  asm("v_cvt_pk_bf16_f32 %0, %1, %2" : "=v"(r) : "v"(lo), "v"(hi));
  return r;
}

// 16B async global->LDS. LDS dest = wave-uniform base + lane*16.
static __device__ __forceinline__ void g2l(const unsigned short* g, short* l) {
  __builtin_amdgcn_global_load_lds(
      (const __attribute__((address_space(1))) void*)g,
      (__attribute__((address_space(3))) void*)l, 16, 0, 0);
}

// XOR swizzle: LDS 16B-block blk of row r holds global 16B-block (blk ^ (r&7)).
#define SWZ_SRC(tid) ((((tid) & 7) ^ (((tid) >> 3) & 7)) << 3)
#define SWZ_RD(B, r) ((((B) ^ ((r) & 7)) << 3))

// ---------- P: cast x + transpose/cast weights, one launch ----------
__global__ __launch_bounds__(256) void prep_all(
    const float* __restrict__ x,
    const float* __restrict__ Wq, const float* __restrict__ Wk,
    const float* __restrict__ Wv, const float* __restrict__ Wo,
    unsigned short* __restrict__ xb,
    unsigned short* __restrict__ Wtq, unsigned short* __restrict__ Wtk,
    unsigned short* __restrict__ Wtv, unsigned short* __restrict__ Wot) {
  __shared__ __align__(16) short Ts[64 * 72];
  const int tid = threadIdx.x;
  const int mat = blockIdx.y;
  if (mat == 4) {
    int base = blockIdx.x * 4096;
#pragma unroll
    for (int i = 0; i < 16; i++) {
      int idx4 = base + tid + i * 256;
      float4 v = *(const float4*)(x + (size_t)idx4 * 4);
      short4v o;
      o[0] = (short)f2bf(v.x); o[1] = (short)f2bf(v.y);
      o[2] = (short)f2bf(v.z); o[3] = (short)f2bf(v.w);
      *(short4v*)(xb + (size_t)idx4 * 4) = o;
    }
    return;
  }
  const float* src;
  unsigned short* dst;
  int r0, c0;
  if (mat < 3) {
    src = (mat == 0) ? Wq : (mat == 1) ? Wk : Wv;
    dst = (mat == 0) ? Wtq : (mat == 1) ? Wtk : Wtv;
    int h = blockIdx.x >> 4;
    int d0 = (blockIdx.x & 15) * 64;
    src += (size_t)(h * DM + d0) * HS;
    dst += (size_t)(h * HS) * DM + d0;
    r0 = HS;  c0 = DM;
  } else {
    src = Wo; dst = Wot;
    int k0 = (blockIdx.x >> 4) * 64;
    int n0 = (blockIdx.x & 15) * 64;
    src += (size_t)k0 * DM + n0;
    dst += (size_t)n0 * DM + k0;
    r0 = DM;  c0 = DM;
  }
#pragma unroll
  for (int i = 0; i < 4; i++) {
    int p = tid + i * 256;
    int row = p >> 4, c4 = (p & 15) << 2;
    float4 v = *(const float4*)(src + (size_t)row * r0 + c4);
    Ts[(c4 + 0) * 72 + row] = (short)f2bf(v.x);
    Ts[(c4 + 1) * 72 + row] = (short)f2bf(v.y);
    Ts[(c4 + 2) * 72 + row] = (short)f2bf(v.z);
    Ts[(c4 + 3) * 72 + row] = (short)f2bf(v.w);
  }
  __syncthreads();
#pragma unroll
  for (int i = 0; i < 2; i++) {
    int p = tid + i * 256;
    int row = p >> 3, c8 = (p & 7) << 3;
    *(short8*)(dst + (size_t)row * c0 + c8) = *(const short8*)&Ts[row * 72 + c8];
  }
}

// ---------- G1: fused QKV GEMM, 128x128 tiles, g2l staging ----------
__global__ __launch_bounds__(256, 3) void qkv_gemm128(
    const unsigned short* __restrict__ xb,
    const unsigned short* __restrict__ Wcat,
    unsigned short* __restrict__ qo,
    unsigned short* __restrict__ ko,
    unsigned short* __restrict__ vo) {
  __shared__ __align__(16) short As[128 * 64];
  __shared__ __align__(16) short Bs[128 * 64];
  const int tid = threadIdx.x;
  const int bm = blockIdx.x, bn = blockIdx.y;
  const int lane = tid & 63, wave = tid >> 6;
  const int quad = lane >> 4, l16 = lane & 15;
  const int wr = wave >> 1, wc = wave & 1;
  const int l7 = l16 & 7;
  const floatx4 fzero = {0.f, 0.f, 0.f, 0.f};

  floatx4 acc[4][4];
#pragma unroll
  for (int i = 0; i < 4; i++)
#pragma unroll
    for (int j = 0; j < 4; j++) acc[i][j] = fzero;

  const int srow = tid >> 3;
  const int scolw = SWZ_SRC(tid);
  const unsigned short* Ag = xb + (size_t)(bm * 128 + srow) * DM + scolw;
  const unsigned short* Bg = Wcat + (size_t)(bn * 128 + srow) * DM + scolw;
  short* Ad = As + tid * 8;
  short* Bd = Bs + tid * 8;

  for (int k0 = 0; k0 < DM; k0 += 64) {
    __syncthreads();
#pragma unroll
    for (int i = 0; i < 4; i++) g2l(Ag + (size_t)i * 32 * DM + k0, Ad + i * 2048);
#pragma unroll
    for (int i = 0; i < 4; i++) g2l(Bg + (size_t)i * 32 * DM + k0, Bd + i * 2048);
    __syncthreads();

    short8 af[4][2], bf[4][2];
#pragma unroll
    for (int ti = 0; ti < 4; ti++)
#pragma unroll
      for (int kh = 0; kh < 2; kh++)
        af[ti][kh] = *(const short8*)&As[(wr * 64 + ti * 16 + l16) * 64 +
                                          SWZ_RD(kh * 4 + quad, l7)];
#pragma unroll
    for (int tj = 0; tj < 4; tj++)
#pragma unroll
      for (int kh = 0; kh < 2; kh++)
        bf[tj][kh] = *(const short8*)&Bs[(wc * 64 + tj * 16 + l16) * 64 +
                                          SWZ_RD(kh * 4 + quad, l7)];
#pragma unroll
    for (int ti = 0; ti < 4; ti++)
#pragma unroll
      for (int tj = 0; tj < 4; tj++) {
        acc[ti][tj] = MFMA(af[ti][0], bf[tj][0], acc[ti][tj]);
        acc[ti][tj] = MFMA(af[ti][1], bf[tj][1], acc[ti][tj]);
      }
  }

  const int mat = bn >> 3;
  const int mbase = bm * 128 + wr * 64 + quad * 4;
  const int nn0 = (bn & 7) * 128 + wc * 64;
  if (mat < 2) {
    unsigned short* dst = (mat == 0) ? qo : ko;
#pragma unroll
    for (int ti = 0; ti < 4; ti++)
#pragma unroll
      for (int tj = 0; tj < 4; tj++) {
        int ecol = nn0 + tj * 16 + l16;
        int h = ecol >> 6, e = ecol & 63;
#pragma unroll
        for (int r = 0; r < 4; r++) {
          int m = mbase + ti * 16 + r;
          int b = m >> 10, t = m & (SEQ - 1);
          dst[((size_t)(b * NH + h) * SEQ + t) * HS + e] = f2bf_fast(acc[ti][tj][r]);
        }
      }
  } else {
#pragma unroll
    for (int ti = 0; ti < 4; ti++)
#pragma unroll
      for (int tj = 0; tj < 4; tj++) {
        int ecol = nn0 + tj * 16 + l16;
        int h = ecol >> 6, e = ecol & 63;
        int m0 = mbase + ti * 16;
        int b = m0 >> 10, t0 = m0 & (SEQ - 1);
        short4v pv;
#pragma unroll
        for (int r = 0; r < 4; r++) pv[r] = (short)f2bf_fast(acc[ti][tj][r]);
        *(short4v*)&vo[((size_t)(b * NH + h) * HS + e) * SEQ + t0] = pv;
      }
  }
}

// ---------- G2: flash attention, 32x32 MFMA, P fully in-register ----------
// R3 post-mortem: 16x16 structure was LDS-pipe-bound (each 16-row wave
// re-reads full K/V tile + P LDS round-trip ~ 40k cyc/CU). This version:
// 32 q-rows/wave (QBLK=128, half the K/V reads per q-row, 18 units/CU),
// swapped QK^T (S^T = mfma(K, Q)) so each lane owns one q-row's P values
// -> P never touches LDS (cvt_pk + shfl_xor(32) assemble PV A-fragments).
// C/D layout 32x32: col = lane&31 (q-row), row = (r&3)+8*(r>>2)+4*(lane>>5).
__global__ __launch_bounds__(256, 2) void attn_kernel(
    const unsigned short* __restrict__ q,   // [B,H,T,HS]
    const unsigned short* __restrict__ k,   // [B,H,T,HS]
    const unsigned short* __restrict__ v,   // [B,H,HS,T]
    unsigned short* __restrict__ o)         // [B,T,H*HS]
{
  __shared__ __align__(16) short Ks[2 * 64 * 64];
  __shared__ __align__(16) short Vt[2 * 64 * 64];
  const int tid = threadIdx.x;
  // Decode: xcd = lid&7 owns heads xcd*8..+7 (L2 locality). u = lid>>3:
  // bhid = xcd*8 + (u&7); qt = (u>>3) for u<32 else 11-(u>>3) so co-resident
  // pairs (lid, lid+256) have qt + qt' = 7 -> 18 units per CU, balanced.
  const int lid = (int)blockIdx.x;
  const int xcd = lid & 7, u = lid >> 3;
  const int bhid = xcd * 8 + (u & 7);
  const int j = u >> 3;
  const int qt = (j < 4) ? j : 11 - j;          // 128-row Q tile index (0..7)
  const int h = bhid & 15, b = bhid >> 4;
  const int lane = tid & 63, wave = tid >> 6;
  const int l32 = lane & 31, hi = lane >> 5;
  const size_t bh = (size_t)(b * NH + h) * SEQ * HS;
  const unsigned short* kbase = k + bh;
  const unsigned short* vbase = v + (size_t)(b * NH + h) * HS * SEQ;
  const float c2 = 0.125f * 1.44269504089f;   // scale * log2(e)
  const float C0 = 16.0f * 1.44269504089f;    // fixed softmax max
  const int srow = tid >> 3;                  // 0..31
  const int scolw = SWZ_SRC(tid);
  const int qbw = qt * 128 + wave * 32;       // wave's first q row (global)

  // Q B-fragments from global: lane holds Q[qbw + l32][ds*16 + hi*8 .. +7].
  short8 qb[4];
#pragma unroll
  for (int ds = 0; ds < 4; ds++)
    qb[ds] = *(const short8*)(q + bh + (size_t)(qbw + l32) * HS + ds * 16 + hi * 8);

  // Prologue: stage K/V tile 0 into buffer 0.
#pragma unroll
  for (int i = 0; i < 2; i++) {
    g2l(kbase + (size_t)(srow + i * 32) * HS + scolw, Ks + tid * 8 + i * 2048);
    g2l(vbase + (size_t)(srow + i * 32) * SEQ + scolw, Vt + tid * 8 + i * 2048);
  }
  __syncthreads();

  float l_ = 0.f;
  floatx16 O0, O1;
#pragma unroll
  for (int i = 0; i < 16; i++) { O0[i] = 0.f; O1[i] = 0.f; }

  const int ktmax = 2 * qt + 1;
  int cur = 0;
  for (int kt = 0; kt <= ktmax; kt++) {
    if (kt < ktmax) {   // stage kt+1 into other buffer; waits land at barrier
      const int nb = cur ^ 1;
#pragma unroll
      for (int i = 0; i < 2; i++) {
        g2l(kbase + (size_t)(kt + 1) * 64 * HS + (size_t)(srow + i * 32) * HS + scolw,
            Ks + nb * 4096 + tid * 8 + i * 2048);
        g2l(vbase + (size_t)(srow + i * 32) * SEQ + (kt + 1) * 64 + scolw,
            Vt + nb * 4096 + tid * 8 + i * 2048);
      }
    }
    const short* Kc = Ks + cur * 4096;
    const short* Vc = Vt + cur * 4096;

    if (kt * 64 <= qbw + 31) {   // wave has unmasked rows in this tile
      // S^T = K Q^T  (A = K rows, B = Q rows; D col = q-row = l32)
      floatx16 S0, S1;
#pragma unroll
      for (int i = 0; i < 16; i++) { S0[i] = 0.f; S1[i] = 0.f; }
#pragma unroll
      for (int ds = 0; ds < 4; ds++) {
        short8 a0 = *(const short8*)&Kc[l32 * 64 + SWZ_RD(ds * 2 + hi, l32)];
        short8 a1 = *(const short8*)&Kc[(32 + l32) * 64 + SWZ_RD(ds * 2 + hi, l32)];
        S0 = MFMA32(a0, qb[ds], S0);
        S1 = MFMA32(a1, qb[ds], S1);
      }
      if (kt * 64 + 63 > qbw) {   // partial causal tile for this wave
        const int qg = qbw + l32;
#pragma unroll
        for (int r = 0; r < 16; r++) {
          int crow = (r & 3) + 8 * (r >> 2) + 4 * hi;
          if (kt * 64 + crow > qg) S0[r] = -INFINITY;
          if (kt * 64 + 32 + crow > qg) S1[r] = -INFINITY;
        }
      }
      // Fixed-max exp; lane accumulates its half of the row sum.
#pragma unroll
      for (int r = 0; r < 16; r++) {
        float p0 = __builtin_amdgcn_exp2f(S0[r] * c2 - C0);
        float p1 = __builtin_amdgcn_exp2f(S1[r] * c2 - C0);
        l_ += p0 + p1;
        S0[r] = p0; S1[r] = p1;
      }
      // Pack to bf16 pairs: cpX[j] = pack(P[2j] lo, P[2j+1] hi).
      unsigned cp0[8], cp1[8];
#pragma unroll
      for (int j2 = 0; j2 < 8; j2++) {
        cp0[j2] = cvtpk(S0[2 * j2], S0[2 * j2 + 1]);
        cp1[j2] = cvtpk(S1[2 * j2], S1[2 * j2 + 1]);
      }
      // PV: assemble A-fragment pa[ks] (P[q=l32][k=ks*16+hi*8..+7]) via one
      // pre-select + shfl_xor(32) per word-pair, then 2 MFMAs per ks.
#pragma unroll
      for (int ks = 0; ks < 4; ks++) {
        const int jb = (ks & 1) * 4;
        unsigned ca = (ks < 2) ? cp0[jb + 0] : cp1[jb + 0];
        unsigned cb = (ks < 2) ? cp0[jb + 1] : cp1[jb + 1];
        unsigned cc = (ks < 2) ? cp0[jb + 2] : cp1[jb + 2];
        unsigned cd = (ks < 2) ? cp0[jb + 3] : cp1[jb + 3];
        unsigned zA = hi ? ca : cc;
        unsigned zB = hi ? cb : cd;
        unsigned sA = __shfl_xor(zA, 32);   // low: partner ca ; hi: partner cc
        unsigned sB = __shfl_xor(zB, 32);
        union { unsigned w[4]; short8 s; } pu;
        pu.w[0] = hi ? sA : ca;
        pu.w[1] = hi ? sB : cb;
        pu.w[2] = hi ? cc : sA;
        pu.w[3] = hi ? cd : sB;
        short8 b0 = *(const short8*)&Vc[l32 * 64 + SWZ_RD(ks * 2 + hi, l32)];
        short8 b1 = *(const short8*)&Vc[(32 + l32) * 64 + SWZ_RD(ks * 2 + hi, l32)];
        O0 = MFMA32(pu.s, b0, O0);
        O1 = MFMA32(pu.s, b1, O1);
      }
    }

    if (kt < ktmax) {
      __syncthreads();   // publishes staged buffer + protects current one
      cur ^= 1;
    }
  }

  // Epilogue: row sum = own half + partner half; rescale + scalar stores.
  float lt = l_ + __shfl_xor(l_, 32);
  float inv = 1.0f / lt;
#pragma unroll
  for (int r = 0; r < 16; r++) {
    int crow = (r & 3) + 8 * (r >> 2) + 4 * hi;   // q-row within wave's 32
    float ivr = __shfl(inv, crow);                 // lane 'crow' holds that row
    unsigned short* dst =
        o + ((size_t)(b * SEQ + qbw + crow)) * DM + h * HS + l32;
    dst[0] = f2bf_fast(O0[r] * ivr);
    dst[32] = f2bf_fast(O1[r] * ivr);
  }
}

// ---------- G3: output projection, 128x128 tiles, g2l staging ----------
// BN 64->128: A re-read 16->8 (global operand traffic 208->144 MB), double
// MFMA per staged byte. Structure cloned from qkv_gemm128.
__global__ __launch_bounds__(256, 3) void out_gemm128(
    const unsigned short* __restrict__ A,    // [4096][1024] bf16
    const unsigned short* __restrict__ Bt,   // Wot [n][k]
    const float* __restrict__ bo,
    float* __restrict__ out) {
  __shared__ __align__(16) short As[128 * 64];
  __shared__ __align__(16) short Bs[128 * 64];
  const int tid = threadIdx.x;
  const int bm = blockIdx.x, bn = blockIdx.y;
  const int lane = tid & 63, wave = tid >> 6;
  const int quad = lane >> 4, l16 = lane & 15;
  const int wr = wave >> 1, wc = wave & 1;
  const int l7 = l16 & 7;
  const floatx4 fzero = {0.f, 0.f, 0.f, 0.f};

  floatx4 acc[4][4];
#pragma unroll
  for (int i = 0; i < 4; i++)
#pragma unroll
    for (int j = 0; j < 4; j++) acc[i][j] = fzero;

  const int srow = tid >> 3;
  const int scolw = SWZ_SRC(tid);
  const unsigned short* Ag = A + (size_t)(bm * 128 + srow) * DM + scolw;
  const unsigned short* Bg = Bt + (size_t)(bn * 128 + srow) * DM + scolw;
  short* Ad = As + tid * 8;
  short* Bd = Bs + tid * 8;

  for (int k0 = 0; k0 < DM; k0 += 64) {
    __syncthreads();
#pragma unroll
    for (int i = 0; i < 4; i++) g2l(Ag + (size_t)i * 32 * DM + k0, Ad + i * 2048);
#pragma unroll
    for (int i = 0; i < 4; i++) g2l(Bg + (size_t)i * 32 * DM + k0, Bd + i * 2048);
    __syncthreads();

    short8 af[4][2], bf[4][2];
#pragma unroll
    for (int ti = 0; ti < 4; ti++)
#pragma unroll
      for (int kh = 0; kh < 2; kh++)
        af[ti][kh] = *(const short8*)&As[(wr * 64 + ti * 16 + l16) * 64 +
                                          SWZ_RD(kh * 4 + quad, l7)];
#pragma unroll
    for (int tj = 0; tj < 4; tj++)
#pragma unroll
      for (int kh = 0; kh < 2; kh++)
        bf[tj][kh] = *(const short8*)&Bs[(wc * 64 + tj * 16 + l16) * 64 +
                                          SWZ_RD(kh * 4 + quad, l7)];
#pragma unroll
    for (int ti = 0; ti < 4; ti++)
#pragma unroll
      for (int tj = 0; tj < 4; tj++) {
        acc[ti][tj] = MFMA(af[ti][0], bf[tj][0], acc[ti][tj]);
        acc[ti][tj] = MFMA(af[ti][1], bf[tj][1], acc[ti][tj]);
      }
  }

#pragma unroll
  for (int ti = 0; ti < 4; ti++)
#pragma unroll
    for (int tj = 0; tj < 4; tj++) {
      int n = bn * 128 + wc * 64 + tj * 16 + l16;
      float bias = bo[n];
#pragma unroll
      for (int r = 0; r < 4; r++) {
        int m = bm * 128 + wr * 64 + ti * 16 + quad * 4 + r;
        out[(size_t)m * DM + n] = acc[ti][tj][r] + bias;
      }
    }
}

extern "C" void kernel_launch(void* const* d_in, const int* in_sizes, int n_in,
                              void* d_out, int out_size, void* d_ws, size_t ws_size,
                              hipStream_t stream) {
  const float* x  = (const float*)d_in[0];
  const float* Wq = (const float*)d_in[1];
  const float* Wk = (const float*)d_in[2];
  const float* Wv = (const float*)d_in[3];
  const float* Wo = (const float*)d_in[4];
  const float* bo = (const float*)d_in[5];
  float* out = (float*)d_out;

  const size_t nx = (size_t)NB * SEQ * DM;          // 4M
  const size_t nw = (size_t)DM * DM;                // 1M
  unsigned short* xb  = (unsigned short*)d_ws;
  unsigned short* wtq = xb + nx;                    // wtq|wtk|wtv contiguous
  unsigned short* wtk = wtq + nw;
  unsigned short* wtv = wtk + nw;
  unsigned short* wot = wtv + nw;
  unsigned short* qws = wot + nw;
  unsigned short* kws = qws + nx;
  unsigned short* vws = kws + nx;
  unsigned short* aws = vws + nx;

  prep_all<<<dim3(256, 5), dim3(256), 0, stream>>>(x, Wq, Wk, Wv, Wo,
                                                   xb, wtq, wtk, wtv, wot);
  qkv_gemm128<<<dim3(32, 24), dim3(256), 0, stream>>>(xb, wtq, qws, kws, vws);
  attn_kernel<<<dim3(512), dim3(256), 0, stream>>>(qws, kws, vws, aws);
  out_gemm128<<<dim3(32, 8), dim3(256), 0, stream>>>(aws, wot, bo, out);
}

// Round 5
// 149.780 us; speedup vs baseline: 1.0464x; 1.0464x over previous
//
#include <hip/hip_runtime.h>
#include <math.h>

#define NB 4
#define SEQ 1024
#define DM 1024
#define NH 16
#define HS 64

typedef __attribute__((ext_vector_type(8))) short short8;
typedef __attribute__((ext_vector_type(4))) short short4v;
typedef __attribute__((ext_vector_type(4))) float floatx4;
typedef __attribute__((ext_vector_type(16))) float floatx16;

#define MFMA(a, b, c) __builtin_amdgcn_mfma_f32_16x16x32_bf16((a), (b), (c), 0, 0, 0)
#define MFMA32(a, b, c) __builtin_amdgcn_mfma_f32_32x32x16_bf16((a), (b), (c), 0, 0, 0)

static __device__ __forceinline__ unsigned short f2bf(float f) {
  unsigned int u = __float_as_uint(f);
  u += 0x7FFFu + ((u >> 16) & 1u);   // RNE (used in weight prep)
  return (unsigned short)(u >> 16);
}
// Cheap biased-RN bf16 (1 add + hi16). <=0.5 ulp vs RNE; finite inputs only.
static __device__ __forceinline__ unsigned short f2bf_fast(float f) {
  return (unsigned short)((__float_as_uint(f) + 0x8000u) >> 16);
}
// v_cvt_pk_bf16_f32: dst.lo16 = bf16(lo), dst.hi16 = bf16(hi). No builtin (m240).
static __device__ __forceinline__ unsigned cvtpk(float lo, float hi) {
  unsigned r;
  asm("v_cvt_pk_bf16_f32 %0, %1, %2" : "=v"(r) : "v"(lo), "v"(hi));
  return r;
}

// 16B async global->LDS. LDS dest = wave-uniform base + lane*16.
static __device__ __forceinline__ void g2l(const unsigned short* g, short* l) {
  __builtin_amdgcn_global_load_lds(
      (const __attribute__((address_space(1))) void*)g,
      (__attribute__((address_space(3))) void*)l, 16, 0, 0);
}

// XOR swizzle: LDS 16B-block blk of row r holds global 16B-block (blk ^ (r&7)).
#define SWZ_SRC(tid) ((((tid) & 7) ^ (((tid) >> 3) & 7)) << 3)
#define SWZ_RD(B, r) ((((B) ^ ((r) & 7)) << 3))

// ---------- P: cast x + transpose/cast weights, one launch ----------
__global__ __launch_bounds__(256) void prep_all(
    const float* __restrict__ x,
    const float* __restrict__ Wq, const float* __restrict__ Wk,
    const float* __restrict__ Wv, const float* __restrict__ Wo,
    unsigned short* __restrict__ xb,
    unsigned short* __restrict__ Wtq, unsigned short* __restrict__ Wtk,
    unsigned short* __restrict__ Wtv, unsigned short* __restrict__ Wot) {
  __shared__ __align__(16) short Ts[64 * 72];
  const int tid = threadIdx.x;
  const int mat = blockIdx.y;
  if (mat == 4) {
    int base = blockIdx.x * 4096;
#pragma unroll
    for (int i = 0; i < 16; i++) {
      int idx4 = base + tid + i * 256;
      float4 v = *(const float4*)(x + (size_t)idx4 * 4);
      short4v o;
      o[0] = (short)f2bf(v.x); o[1] = (short)f2bf(v.y);
      o[2] = (short)f2bf(v.z); o[3] = (short)f2bf(v.w);
      *(short4v*)(xb + (size_t)idx4 * 4) = o;
    }
    return;
  }
  const float* src;
  unsigned short* dst;
  int r0, c0;
  if (mat < 3) {
    src = (mat == 0) ? Wq : (mat == 1) ? Wk : Wv;
    dst = (mat == 0) ? Wtq : (mat == 1) ? Wtk : Wtv;
    int h = blockIdx.x >> 4;
    int d0 = (blockIdx.x & 15) * 64;
    src += (size_t)(h * DM + d0) * HS;
    dst += (size_t)(h * HS) * DM + d0;
    r0 = HS;  c0 = DM;
  } else {
    src = Wo; dst = Wot;
    int k0 = (blockIdx.x >> 4) * 64;
    int n0 = (blockIdx.x & 15) * 64;
    src += (size_t)k0 * DM + n0;
    dst += (size_t)n0 * DM + k0;
    r0 = DM;  c0 = DM;
  }
#pragma unroll
  for (int i = 0; i < 4; i++) {
    int p = tid + i * 256;
    int row = p >> 4, c4 = (p & 15) << 2;
    float4 v = *(const float4*)(src + (size_t)row * r0 + c4);
    Ts[(c4 + 0) * 72 + row] = (short)f2bf(v.x);
    Ts[(c4 + 1) * 72 + row] = (short)f2bf(v.y);
    Ts[(c4 + 2) * 72 + row] = (short)f2bf(v.z);
    Ts[(c4 + 3) * 72 + row] = (short)f2bf(v.w);
  }
  __syncthreads();
#pragma unroll
  for (int i = 0; i < 2; i++) {
    int p = tid + i * 256;
    int row = p >> 3, c8 = (p & 7) << 3;
    *(short8*)(dst + (size_t)row * c0 + c8) = *(const short8*)&Ts[row * 72 + c8];
  }
}

// ---------- G1: fused QKV GEMM, 128x128 tiles, g2l staging ----------
__global__ __launch_bounds__(256, 3) void qkv_gemm128(
    const unsigned short* __restrict__ xb,
    const unsigned short* __restrict__ Wcat,
    unsigned short* __restrict__ qo,
    unsigned short* __restrict__ ko,
    unsigned short* __restrict__ vo) {
  __shared__ __align__(16) short As[128 * 64];
  __shared__ __align__(16) short Bs[128 * 64];
  const int tid = threadIdx.x;
  const int bm = blockIdx.x, bn = blockIdx.y;
  const int lane = tid & 63, wave = tid >> 6;
  const int quad = lane >> 4, l16 = lane & 15;
  const int wr = wave >> 1, wc = wave & 1;
  const int l7 = l16 & 7;
  const floatx4 fzero = {0.f, 0.f, 0.f, 0.f};

  floatx4 acc[4][4];
#pragma unroll
  for (int i = 0; i < 4; i++)
#pragma unroll
    for (int j = 0; j < 4; j++) acc[i][j] = fzero;

  const int srow = tid >> 3;
  const int scolw = SWZ_SRC(tid);
  const unsigned short* Ag = xb + (size_t)(bm * 128 + srow) * DM + scolw;
  const unsigned short* Bg = Wcat + (size_t)(bn * 128 + srow) * DM + scolw;
  short* Ad = As + tid * 8;
  short* Bd = Bs + tid * 8;

  for (int k0 = 0; k0 < DM; k0 += 64) {
    __syncthreads();
#pragma unroll
    for (int i = 0; i < 4; i++) g2l(Ag + (size_t)i * 32 * DM + k0, Ad + i * 2048);
#pragma unroll
    for (int i = 0; i < 4; i++) g2l(Bg + (size_t)i * 32 * DM + k0, Bd + i * 2048);
    __syncthreads();

    short8 af[4][2], bf[4][2];
#pragma unroll
    for (int ti = 0; ti < 4; ti++)
#pragma unroll
      for (int kh = 0; kh < 2; kh++)
        af[ti][kh] = *(const short8*)&As[(wr * 64 + ti * 16 + l16) * 64 +
                                          SWZ_RD(kh * 4 + quad, l7)];
#pragma unroll
    for (int tj = 0; tj < 4; tj++)
#pragma unroll
      for (int kh = 0; kh < 2; kh++)
        bf[tj][kh] = *(const short8*)&Bs[(wc * 64 + tj * 16 + l16) * 64 +
                                          SWZ_RD(kh * 4 + quad, l7)];
#pragma unroll
    for (int ti = 0; ti < 4; ti++)
#pragma unroll
      for (int tj = 0; tj < 4; tj++) {
        acc[ti][tj] = MFMA(af[ti][0], bf[tj][0], acc[ti][tj]);
        acc[ti][tj] = MFMA(af[ti][1], bf[tj][1], acc[ti][tj]);
      }
  }

  const int mat = bn >> 3;
  const int mbase = bm * 128 + wr * 64 + quad * 4;
  const int nn0 = (bn & 7) * 128 + wc * 64;
  if (mat < 2) {
    unsigned short* dst = (mat == 0) ? qo : ko;
#pragma unroll
    for (int ti = 0; ti < 4; ti++)
#pragma unroll
      for (int tj = 0; tj < 4; tj++) {
        int ecol = nn0 + tj * 16 + l16;
        int h = ecol >> 6, e = ecol & 63;
#pragma unroll
        for (int r = 0; r < 4; r++) {
          int m = mbase + ti * 16 + r;
          int b = m >> 10, t = m & (SEQ - 1);
          dst[((size_t)(b * NH + h) * SEQ + t) * HS + e] = f2bf_fast(acc[ti][tj][r]);
        }
      }
  } else {
#pragma unroll
    for (int ti = 0; ti < 4; ti++)
#pragma unroll
      for (int tj = 0; tj < 4; tj++) {
        int ecol = nn0 + tj * 16 + l16;
        int h = ecol >> 6, e = ecol & 63;
        int m0 = mbase + ti * 16;
        int b = m0 >> 10, t0 = m0 & (SEQ - 1);
        short4v pv;
#pragma unroll
        for (int r = 0; r < 4; r++) pv[r] = (short)f2bf_fast(acc[ti][tj][r]);
        *(short4v*)&vo[((size_t)(b * NH + h) * HS + e) * SEQ + t0] = pv;
      }
  }
}

// ---------- G2: flash attention, 32x32 MFMA, P fully in-register ----------
// (byte-identical to R4 — under isolation test this round)
__global__ __launch_bounds__(256, 2) void attn_kernel(
    const unsigned short* __restrict__ q,   // [B,H,T,HS]
    const unsigned short* __restrict__ k,   // [B,H,T,HS]
    const unsigned short* __restrict__ v,   // [B,H,HS,T]
    unsigned short* __restrict__ o)         // [B,T,H*HS]
{
  __shared__ __align__(16) short Ks[2 * 64 * 64];
  __shared__ __align__(16) short Vt[2 * 64 * 64];
  const int tid = threadIdx.x;
  const int lid = (int)blockIdx.x;
  const int xcd = lid & 7, u = lid >> 3;
  const int bhid = xcd * 8 + (u & 7);
  const int j = u >> 3;
  const int qt = (j < 4) ? j : 11 - j;          // 128-row Q tile index (0..7)
  const int h = bhid & 15, b = bhid >> 4;
  const int lane = tid & 63, wave = tid >> 6;
  const int l32 = lane & 31, hi = lane >> 5;
  const size_t bh = (size_t)(b * NH + h) * SEQ * HS;
  const unsigned short* kbase = k + bh;
  const unsigned short* vbase = v + (size_t)(b * NH + h) * HS * SEQ;
  const float c2 = 0.125f * 1.44269504089f;   // scale * log2(e)
  const float C0 = 16.0f * 1.44269504089f;    // fixed softmax max
  const int srow = tid >> 3;                  // 0..31
  const int scolw = SWZ_SRC(tid);
  const int qbw = qt * 128 + wave * 32;       // wave's first q row (global)

  // Q B-fragments from global: lane holds Q[qbw + l32][ds*16 + hi*8 .. +7].
  short8 qb[4];
#pragma unroll
  for (int ds = 0; ds < 4; ds++)
    qb[ds] = *(const short8*)(q + bh + (size_t)(qbw + l32) * HS + ds * 16 + hi * 8);

  // Prologue: stage K/V tile 0 into buffer 0.
#pragma unroll
  for (int i = 0; i < 2; i++) {
    g2l(kbase + (size_t)(srow + i * 32) * HS + scolw, Ks + tid * 8 + i * 2048);
    g2l(vbase + (size_t)(srow + i * 32) * SEQ + scolw, Vt + tid * 8 + i * 2048);
  }
  __syncthreads();

  float l_ = 0.f;
  floatx16 O0, O1;
#pragma unroll
  for (int i = 0; i < 16; i++) { O0[i] = 0.f; O1[i] = 0.f; }

  const int ktmax = 2 * qt + 1;
  int cur = 0;
  for (int kt = 0; kt <= ktmax; kt++) {
    if (kt < ktmax) {   // stage kt+1 into other buffer; waits land at barrier
      const int nb = cur ^ 1;
#pragma unroll
      for (int i = 0; i < 2; i++) {
        g2l(kbase + (size_t)(kt + 1) * 64 * HS + (size_t)(srow + i * 32) * HS + scolw,
            Ks + nb * 4096 + tid * 8 + i * 2048);
        g2l(vbase + (size_t)(srow + i * 32) * SEQ + (kt + 1) * 64 + scolw,
            Vt + nb * 4096 + tid * 8 + i * 2048);
      }
    }
    const short* Kc = Ks + cur * 4096;
    const short* Vc = Vt + cur * 4096;

    if (kt * 64 <= qbw + 31) {   // wave has unmasked rows in this tile
      // S^T = K Q^T  (A = K rows, B = Q rows; D col = q-row = l32)
      floatx16 S0, S1;
#pragma unroll
      for (int i = 0; i < 16; i++) { S0[i] = 0.f; S1[i] = 0.f; }
#pragma unroll
      for (int ds = 0; ds < 4; ds++) {
        short8 a0 = *(const short8*)&Kc[l32 * 64 + SWZ_RD(ds * 2 + hi, l32)];
        short8 a1 = *(const short8*)&Kc[(32 + l32) * 64 + SWZ_RD(ds * 2 + hi, l32)];
        S0 = MFMA32(a0, qb[ds], S0);
        S1 = MFMA32(a1, qb[ds], S1);
      }
      if (kt * 64 + 63 > qbw) {   // partial causal tile for this wave
        const int qg = qbw + l32;
#pragma unroll
        for (int r = 0; r < 16; r++) {
          int crow = (r & 3) + 8 * (r >> 2) + 4 * hi;
          if (kt * 64 + crow > qg) S0[r] = -INFINITY;
          if (kt * 64 + 32 + crow > qg) S1[r] = -INFINITY;
        }
      }
      // Fixed-max exp; lane accumulates its half of the row sum.
#pragma unroll
      for (int r = 0; r < 16; r++) {
        float p0 = __builtin_amdgcn_exp2f(S0[r] * c2 - C0);
        float p1 = __builtin_amdgcn_exp2f(S1[r] * c2 - C0);
        l_ += p0 + p1;
        S0[r] = p0; S1[r] = p1;
      }
      // Pack to bf16 pairs: cpX[j] = pack(P[2j] lo, P[2j+1] hi).
      unsigned cp0[8], cp1[8];
#pragma unroll
      for (int j2 = 0; j2 < 8; j2++) {
        cp0[j2] = cvtpk(S0[2 * j2], S0[2 * j2 + 1]);
        cp1[j2] = cvtpk(S1[2 * j2], S1[2 * j2 + 1]);
      }
      // PV: assemble A-fragment pa[ks] (P[q=l32][k=ks*16+hi*8..+7]) via one
      // pre-select + shfl_xor(32) per word-pair, then 2 MFMAs per ks.
#pragma unroll
      for (int ks = 0; ks < 4; ks++) {
        const int jb = (ks & 1) * 4;
        unsigned ca = (ks < 2) ? cp0[jb + 0] : cp1[jb + 0];
        unsigned cb = (ks < 2) ? cp0[jb + 1] : cp1[jb + 1];
        unsigned cc = (ks < 2) ? cp0[jb + 2] : cp1[jb + 2];
        unsigned cd = (ks < 2) ? cp0[jb + 3] : cp1[jb + 3];
        unsigned zA = hi ? ca : cc;
        unsigned zB = hi ? cb : cd;
        unsigned sA = __shfl_xor(zA, 32);   // low: partner ca ; hi: partner cc
        unsigned sB = __shfl_xor(zB, 32);
        union { unsigned w[4]; short8 s; } pu;
        pu.w[0] = hi ? sA : ca;
        pu.w[1] = hi ? sB : cb;
        pu.w[2] = hi ? cc : sA;
        pu.w[3] = hi ? cd : sB;
        short8 b0 = *(const short8*)&Vc[l32 * 64 + SWZ_RD(ks * 2 + hi, l32)];
        short8 b1 = *(const short8*)&Vc[(32 + l32) * 64 + SWZ_RD(ks * 2 + hi, l32)];
        O0 = MFMA32(pu.s, b0, O0);
        O1 = MFMA32(pu.s, b1, O1);
      }
    }

    if (kt < ktmax) {
      __syncthreads();   // publishes staged buffer + protects current one
      cur ^= 1;
    }
  }

  // Epilogue: row sum = own half + partner half; rescale + scalar stores.
  float lt = l_ + __shfl_xor(l_, 32);
  float inv = 1.0f / lt;
#pragma unroll
  for (int r = 0; r < 16; r++) {
    int crow = (r & 3) + 8 * (r >> 2) + 4 * hi;   // q-row within wave's 32
    float ivr = __shfl(inv, crow);                 // lane 'crow' holds that row
    unsigned short* dst =
        o + ((size_t)(b * SEQ + qbw + crow)) * DM + h * HS + l32;
    dst[0] = f2bf_fast(O0[r] * ivr);
    dst[32] = f2bf_fast(O1[r] * ivr);
  }
}

// ---------- G3: output projection, 128x64 tiles (R3-proven config) ----------
// R4 post-mortem suspect: 128x128 grid had 256 blocks = 1 block/CU -> the
// per-k-step vmcnt(0) barrier drain had no co-resident block to hide under.
// Reverted to the measured R3 config (512 blocks = 2 blocks/CU).
__global__ __launch_bounds__(256, 3) void out_gemm64(
    const unsigned short* __restrict__ A,    // [4096][1024] bf16
    const unsigned short* __restrict__ Bt,   // Wot [n][k]
    const float* __restrict__ bo,
    float* __restrict__ out) {
  __shared__ __align__(16) short As[128 * 64];
  __shared__ __align__(16) short Bs[64 * 64];
  const int tid = threadIdx.x;
  const int bm = blockIdx.x, bn = blockIdx.y;
  const int lane = tid & 63, wave = tid >> 6;
  const int quad = lane >> 4, l16 = lane & 15;
  const int wr = wave >> 1, wc = wave & 1;
  const int l7 = l16 & 7;
  const floatx4 fzero = {0.f, 0.f, 0.f, 0.f};

  floatx4 acc[4][2];
#pragma unroll
  for (int i = 0; i < 4; i++)
#pragma unroll
    for (int j = 0; j < 2; j++) acc[i][j] = fzero;

  const int srow = tid >> 3;
  const int scolw = SWZ_SRC(tid);
  const unsigned short* Ag = A + (size_t)(bm * 128 + srow) * DM + scolw;
  const unsigned short* Bg = Bt + (size_t)(bn * 64 + srow) * DM + scolw;
  short* Ad = As + tid * 8;
  short* Bd = Bs + tid * 8;

  for (int k0 = 0; k0 < DM; k0 += 64) {
    __syncthreads();
#pragma unroll
    for (int i = 0; i < 4; i++) g2l(Ag + (size_t)i * 32 * DM + k0, Ad + i * 2048);
#pragma unroll
    for (int i = 0; i < 2; i++) g2l(Bg + (size_t)i * 32 * DM + k0, Bd + i * 2048);
    __syncthreads();

    short8 af[4][2], bf[2][2];
#pragma unroll
    for (int ti = 0; ti < 4; ti++)
#pragma unroll
      for (int kh = 0; kh < 2; kh++)
        af[ti][kh] = *(const short8*)&As[(wr * 64 + ti * 16 + l16) * 64 +
                                          SWZ_RD(kh * 4 + quad, l7)];
#pragma unroll
    for (int tj = 0; tj < 2; tj++)
#pragma unroll
      for (int kh = 0; kh < 2; kh++)
        bf[tj][kh] = *(const short8*)&Bs[(wc * 32 + tj * 16 + l16) * 64 +
                                          SWZ_RD(kh * 4 + quad, l7)];
#pragma unroll
    for (int ti = 0; ti < 4; ti++)
#pragma unroll
      for (int tj = 0; tj < 2; tj++) {
        acc[ti][tj] = MFMA(af[ti][0], bf[tj][0], acc[ti][tj]);
        acc[ti][tj] = MFMA(af[ti][1], bf[tj][1], acc[ti][tj]);
      }
  }

#pragma unroll
  for (int ti = 0; ti < 4; ti++)
#pragma unroll
    for (int tj = 0; tj < 2; tj++) {
      int n = bn * 64 + wc * 32 + tj * 16 + l16;
      float bias = bo[n];
#pragma unroll
      for (int r = 0; r < 4; r++) {
        int m = bm * 128 + wr * 64 + ti * 16 + quad * 4 + r;
        out[(size_t)m * DM + n] = acc[ti][tj][r] + bias;
      }
    }
}

extern "C" void kernel_launch(void* const* d_in, const int* in_sizes, int n_in,
                              void* d_out, int out_size, void* d_ws, size_t ws_size,
                              hipStream_t stream) {
  const float* x  = (const float*)d_in[0];
  const float* Wq = (const float*)d_in[1];
  const float* Wk = (const float*)d_in[2];
  const float* Wv = (const float*)d_in[3];
  const float* Wo = (const float*)d_in[4];
  const float* bo = (const float*)d_in[5];
  float* out = (float*)d_out;

  const size_t nx = (size_t)NB * SEQ * DM;          // 4M
  const size_t nw = (size_t)DM * DM;                // 1M
  unsigned short* xb  = (unsigned short*)d_ws;
  unsigned short* wtq = xb + nx;                    // wtq|wtk|wtv contiguous
  unsigned short* wtk = wtq + nw;
  unsigned short* wtv = wtk + nw;
  unsigned short* wot = wtv + nw;
  unsigned short* qws = wot + nw;
  unsigned short* kws = qws + nx;
  unsigned short* vws = kws + nx;
  unsigned short* aws = vws + nx;

  prep_all<<<dim3(256, 5), dim3(256), 0, stream>>>(x, Wq, Wk, Wv, Wo,
                                                   xb, wtq, wtk, wtv, wot);
  qkv_gemm128<<<dim3(32, 24), dim3(256), 0, stream>>>(xb, wtq, qws, kws, vws);
  attn_kernel<<<dim3(512), dim3(256), 0, stream>>>(qws, kws, vws, aws);
  out_gemm64<<<dim3(32, 16), dim3(256), 0, stream>>>(aws, wot, bo, out);
}

// Round 6
// 149.766 us; speedup vs baseline: 1.0465x; 1.0001x over previous
//
#include <hip/hip_runtime.h>
#include <math.h>

#define NB 4
#define SEQ 1024
#define DM 1024
#define NH 16
#define HS 64

typedef __attribute__((ext_vector_type(8))) short short8;
typedef __attribute__((ext_vector_type(4))) short short4v;
typedef __attribute__((ext_vector_type(4))) float floatx4;
typedef __attribute__((ext_vector_type(16))) float floatx16;

#define MFMA(a, b, c) __builtin_amdgcn_mfma_f32_16x16x32_bf16((a), (b), (c), 0, 0, 0)
#define MFMA32(a, b, c) __builtin_amdgcn_mfma_f32_32x32x16_bf16((a), (b), (c), 0, 0, 0)

static __device__ __forceinline__ unsigned short f2bf(float f) {
  unsigned int u = __float_as_uint(f);
  u += 0x7FFFu + ((u >> 16) & 1u);   // RNE (used in weight prep)
  return (unsigned short)(u >> 16);
}
// Cheap biased-RN bf16 (1 add + hi16). <=0.5 ulp vs RNE; finite inputs only.
static __device__ __forceinline__ unsigned short f2bf_fast(float f) {
  return (unsigned short)((__float_as_uint(f) + 0x8000u) >> 16);
}
// v_cvt_pk_bf16_f32: dst.lo16 = bf16(lo), dst.hi16 = bf16(hi). No builtin (m240).
static __device__ __forceinline__ unsigned cvtpk(float lo, float hi) {
  unsigned r;
  asm("v_cvt_pk_bf16_f32 %0, %1, %2" : "=v"(r) : "v"(lo), "v"(hi));
  return r;
}

// 16B async global->LDS. LDS dest = wave-uniform base + lane*16.
static __device__ __forceinline__ void g2l(const unsigned short* g, short* l) {
  __builtin_amdgcn_global_load_lds(
      (const __attribute__((address_space(1))) void*)g,
      (__attribute__((address_space(3))) void*)l, 16, 0, 0);
}

// XOR swizzle: LDS 16B-block blk of row r holds global 16B-block (blk ^ (r&7)).
#define SWZ_SRC(tid) ((((tid) & 7) ^ (((tid) >> 3) & 7)) << 3)
#define SWZ_RD(B, r) ((((B) ^ ((r) & 7)) << 3))

// ---------- P: cast x + transpose/cast weights, one launch ----------
__global__ __launch_bounds__(256) void prep_all(
    const float* __restrict__ x,
    const float* __restrict__ Wq, const float* __restrict__ Wk,
    const float* __restrict__ Wv, const float* __restrict__ Wo,
    unsigned short* __restrict__ xb,
    unsigned short* __restrict__ Wtq, unsigned short* __restrict__ Wtk,
    unsigned short* __restrict__ Wtv, unsigned short* __restrict__ Wot) {
  __shared__ __align__(16) short Ts[64 * 72];
  const int tid = threadIdx.x;
  const int mat = blockIdx.y;
  if (mat == 4) {
    int base = blockIdx.x * 4096;
#pragma unroll
    for (int i = 0; i < 16; i++) {
      int idx4 = base + tid + i * 256;
      float4 v = *(const float4*)(x + (size_t)idx4 * 4);
      short4v o;
      o[0] = (short)f2bf(v.x); o[1] = (short)f2bf(v.y);
      o[2] = (short)f2bf(v.z); o[3] = (short)f2bf(v.w);
      *(short4v*)(xb + (size_t)idx4 * 4) = o;
    }
    return;
  }
  const float* src;
  unsigned short* dst;
  int r0, c0;
  if (mat < 3) {
    src = (mat == 0) ? Wq : (mat == 1) ? Wk : Wv;
    dst = (mat == 0) ? Wtq : (mat == 1) ? Wtk : Wtv;
    int h = blockIdx.x >> 4;
    int d0 = (blockIdx.x & 15) * 64;
    src += (size_t)(h * DM + d0) * HS;
    dst += (size_t)(h * HS) * DM + d0;
    r0 = HS;  c0 = DM;
  } else {
    src = Wo; dst = Wot;
    int k0 = (blockIdx.x >> 4) * 64;
    int n0 = (blockIdx.x & 15) * 64;
    src += (size_t)k0 * DM + n0;
    dst += (size_t)n0 * DM + k0;
    r0 = DM;  c0 = DM;
  }
#pragma unroll
  for (int i = 0; i < 4; i++) {
    int p = tid + i * 256;
    int row = p >> 4, c4 = (p & 15) << 2;
    float4 v = *(const float4*)(src + (size_t)row * r0 + c4);
    Ts[(c4 + 0) * 72 + row] = (short)f2bf(v.x);
    Ts[(c4 + 1) * 72 + row] = (short)f2bf(v.y);
    Ts[(c4 + 2) * 72 + row] = (short)f2bf(v.z);
    Ts[(c4 + 3) * 72 + row] = (short)f2bf(v.w);
  }
  __syncthreads();
#pragma unroll
  for (int i = 0; i < 2; i++) {
    int p = tid + i * 256;
    int row = p >> 3, c8 = (p & 7) << 3;
    *(short8*)(dst + (size_t)row * c0 + c8) = *(const short8*)&Ts[row * 72 + c8];
  }
}

// ---------- G1: fused QKV GEMM, 128x128 tiles, XCD-sliced bm ----------
// R5 analysis: A/B panel re-reads were served cross-XCD from L3 (~5 TB/s,
// 384 MB). Remap: xcd = lid&7 owns bm in [4*xcd, 4*xcd+4) -> per-XCD A
// slice = 1 MB, L2-resident; co-resident blocks on one CU share bm.
__global__ __launch_bounds__(256, 3) void qkv_gemm128(
    const unsigned short* __restrict__ xb,
    const unsigned short* __restrict__ Wcat,
    unsigned short* __restrict__ qo,
    unsigned short* __restrict__ ko,
    unsigned short* __restrict__ vo) {
  __shared__ __align__(16) short As[128 * 64];
  __shared__ __align__(16) short Bs[128 * 64];
  const int tid = threadIdx.x;
  const int lid = (int)blockIdx.x;          // 0..767
  const int xcd = lid & 7, u = lid >> 3;    // u: 0..95
  const int bm = xcd * 4 + (u & 3);
  const int bn = u >> 2;                    // 0..23
  const int lane = tid & 63, wave = tid >> 6;
  const int quad = lane >> 4, l16 = lane & 15;
  const int wr = wave >> 1, wc = wave & 1;
  const int l7 = l16 & 7;
  const floatx4 fzero = {0.f, 0.f, 0.f, 0.f};

  floatx4 acc[4][4];
#pragma unroll
  for (int i = 0; i < 4; i++)
#pragma unroll
    for (int j = 0; j < 4; j++) acc[i][j] = fzero;

  const int srow = tid >> 3;
  const int scolw = SWZ_SRC(tid);
  const unsigned short* Ag = xb + (size_t)(bm * 128 + srow) * DM + scolw;
  const unsigned short* Bg = Wcat + (size_t)(bn * 128 + srow) * DM + scolw;
  short* Ad = As + tid * 8;
  short* Bd = Bs + tid * 8;

  for (int k0 = 0; k0 < DM; k0 += 64) {
    __syncthreads();
#pragma unroll
    for (int i = 0; i < 4; i++) g2l(Ag + (size_t)i * 32 * DM + k0, Ad + i * 2048);
#pragma unroll
    for (int i = 0; i < 4; i++) g2l(Bg + (size_t)i * 32 * DM + k0, Bd + i * 2048);
    __syncthreads();

    short8 af[4][2], bf[4][2];
#pragma unroll
    for (int ti = 0; ti < 4; ti++)
#pragma unroll
      for (int kh = 0; kh < 2; kh++)
        af[ti][kh] = *(const short8*)&As[(wr * 64 + ti * 16 + l16) * 64 +
                                          SWZ_RD(kh * 4 + quad, l7)];
#pragma unroll
    for (int tj = 0; tj < 4; tj++)
#pragma unroll
      for (int kh = 0; kh < 2; kh++)
        bf[tj][kh] = *(const short8*)&Bs[(wc * 64 + tj * 16 + l16) * 64 +
                                          SWZ_RD(kh * 4 + quad, l7)];
#pragma unroll
    for (int ti = 0; ti < 4; ti++)
#pragma unroll
      for (int tj = 0; tj < 4; tj++) {
        acc[ti][tj] = MFMA(af[ti][0], bf[tj][0], acc[ti][tj]);
        acc[ti][tj] = MFMA(af[ti][1], bf[tj][1], acc[ti][tj]);
      }
  }

  const int mat = bn >> 3;
  const int mbase = bm * 128 + wr * 64 + quad * 4;
  const int nn0 = (bn & 7) * 128 + wc * 64;
  if (mat < 2) {
    unsigned short* dst = (mat == 0) ? qo : ko;
#pragma unroll
    for (int ti = 0; ti < 4; ti++)
#pragma unroll
      for (int tj = 0; tj < 4; tj++) {
        int ecol = nn0 + tj * 16 + l16;
        int h = ecol >> 6, e = ecol & 63;
#pragma unroll
        for (int r = 0; r < 4; r++) {
          int m = mbase + ti * 16 + r;
          int b = m >> 10, t = m & (SEQ - 1);
          dst[((size_t)(b * NH + h) * SEQ + t) * HS + e] = f2bf_fast(acc[ti][tj][r]);
        }
      }
  } else {
#pragma unroll
    for (int ti = 0; ti < 4; ti++)
#pragma unroll
      for (int tj = 0; tj < 4; tj++) {
        int ecol = nn0 + tj * 16 + l16;
        int h = ecol >> 6, e = ecol & 63;
        int m0 = mbase + ti * 16;
        int b = m0 >> 10, t0 = m0 & (SEQ - 1);
        short4v pv;
#pragma unroll
        for (int r = 0; r < 4; r++) pv[r] = (short)f2bf_fast(acc[ti][tj][r]);
        *(short4v*)&vo[((size_t)(b * NH + h) * HS + e) * SEQ + t0] = pv;
      }
  }
}

// ---------- G2: flash attention, 32x32 MFMA, P fully in-register ----------
// (byte-identical to R4/R5 — neutral vs attn16, kept)
__global__ __launch_bounds__(256, 2) void attn_kernel(
    const unsigned short* __restrict__ q,   // [B,H,T,HS]
    const unsigned short* __restrict__ k,   // [B,H,T,HS]
    const unsigned short* __restrict__ v,   // [B,H,HS,T]
    unsigned short* __restrict__ o)         // [B,T,H*HS]
{
  __shared__ __align__(16) short Ks[2 * 64 * 64];
  __shared__ __align__(16) short Vt[2 * 64 * 64];
  const int tid = threadIdx.x;
  const int lid = (int)blockIdx.x;
  const int xcd = lid & 7, u = lid >> 3;
  const int bhid = xcd * 8 + (u & 7);
  const int j = u >> 3;
  const int qt = (j < 4) ? j : 11 - j;          // 128-row Q tile index (0..7)
  const int h = bhid & 15, b = bhid >> 4;
  const int lane = tid & 63, wave = tid >> 6;
  const int l32 = lane & 31, hi = lane >> 5;
  const size_t bh = (size_t)(b * NH + h) * SEQ * HS;
  const unsigned short* kbase = k + bh;
  const unsigned short* vbase = v + (size_t)(b * NH + h) * HS * SEQ;
  const float c2 = 0.125f * 1.44269504089f;   // scale * log2(e)
  const float C0 = 16.0f * 1.44269504089f;    // fixed softmax max
  const int srow = tid >> 3;                  // 0..31
  const int scolw = SWZ_SRC(tid);
  const int qbw = qt * 128 + wave * 32;       // wave's first q row (global)

  // Q B-fragments from global: lane holds Q[qbw + l32][ds*16 + hi*8 .. +7].
  short8 qb[4];
#pragma unroll
  for (int ds = 0; ds < 4; ds++)
    qb[ds] = *(const short8*)(q + bh + (size_t)(qbw + l32) * HS + ds * 16 + hi * 8);

  // Prologue: stage K/V tile 0 into buffer 0.
#pragma unroll
  for (int i = 0; i < 2; i++) {
    g2l(kbase + (size_t)(srow + i * 32) * HS + scolw, Ks + tid * 8 + i * 2048);
    g2l(vbase + (size_t)(srow + i * 32) * SEQ + scolw, Vt + tid * 8 + i * 2048);
  }
  __syncthreads();

  float l_ = 0.f;
  floatx16 O0, O1;
#pragma unroll
  for (int i = 0; i < 16; i++) { O0[i] = 0.f; O1[i] = 0.f; }

  const int ktmax = 2 * qt + 1;
  int cur = 0;
  for (int kt = 0; kt <= ktmax; kt++) {
    if (kt < ktmax) {   // stage kt+1 into other buffer; waits land at barrier
      const int nb = cur ^ 1;
#pragma unroll
      for (int i = 0; i < 2; i++) {
        g2l(kbase + (size_t)(kt + 1) * 64 * HS + (size_t)(srow + i * 32) * HS + scolw,
            Ks + nb * 4096 + tid * 8 + i * 2048);
        g2l(vbase + (size_t)(srow + i * 32) * SEQ + (kt + 1) * 64 + scolw,
            Vt + nb * 4096 + tid * 8 + i * 2048);
      }
    }
    const short* Kc = Ks + cur * 4096;
    const short* Vc = Vt + cur * 4096;

    if (kt * 64 <= qbw + 31) {   // wave has unmasked rows in this tile
      // S^T = K Q^T  (A = K rows, B = Q rows; D col = q-row = l32)
      floatx16 S0, S1;
#pragma unroll
      for (int i = 0; i < 16; i++) { S0[i] = 0.f; S1[i] = 0.f; }
#pragma unroll
      for (int ds = 0; ds < 4; ds++) {
        short8 a0 = *(const short8*)&Kc[l32 * 64 + SWZ_RD(ds * 2 + hi, l32)];
        short8 a1 = *(const short8*)&Kc[(32 + l32) * 64 + SWZ_RD(ds * 2 + hi, l32)];
        S0 = MFMA32(a0, qb[ds], S0);
        S1 = MFMA32(a1, qb[ds], S1);
      }
      if (kt * 64 + 63 > qbw) {   // partial causal tile for this wave
        const int qg = qbw + l32;
#pragma unroll
        for (int r = 0; r < 16; r++) {
          int crow = (r & 3) + 8 * (r >> 2) + 4 * hi;
          if (kt * 64 + crow > qg) S0[r] = -INFINITY;
          if (kt * 64 + 32 + crow > qg) S1[r] = -INFINITY;
        }
      }
      // Fixed-max exp; lane accumulates its half of the row sum.
#pragma unroll
      for (int r = 0; r < 16; r++) {
        float p0 = __builtin_amdgcn_exp2f(S0[r] * c2 - C0);
        float p1 = __builtin_amdgcn_exp2f(S1[r] * c2 - C0);
        l_ += p0 + p1;
        S0[r] = p0; S1[r] = p1;
      }
      // Pack to bf16 pairs: cpX[j] = pack(P[2j] lo, P[2j+1] hi).
      unsigned cp0[8], cp1[8];
#pragma unroll
      for (int j2 = 0; j2 < 8; j2++) {
        cp0[j2] = cvtpk(S0[2 * j2], S0[2 * j2 + 1]);
        cp1[j2] = cvtpk(S1[2 * j2], S1[2 * j2 + 1]);
      }
      // PV: assemble A-fragment pa[ks] (P[q=l32][k=ks*16+hi*8..+7]) via one
      // pre-select + shfl_xor(32) per word-pair, then 2 MFMAs per ks.
#pragma unroll
      for (int ks = 0; ks < 4; ks++) {
        const int jb = (ks & 1) * 4;
        unsigned ca = (ks < 2) ? cp0[jb + 0] : cp1[jb + 0];
        unsigned cb = (ks < 2) ? cp0[jb + 1] : cp1[jb + 1];
        unsigned cc = (ks < 2) ? cp0[jb + 2] : cp1[jb + 2];
        unsigned cd = (ks < 2) ? cp0[jb + 3] : cp1[jb + 3];
        unsigned zA = hi ? ca : cc;
        unsigned zB = hi ? cb : cd;
        unsigned sA = __shfl_xor(zA, 32);   // low: partner ca ; hi: partner cc
        unsigned sB = __shfl_xor(zB, 32);
        union { unsigned w[4]; short8 s; } pu;
        pu.w[0] = hi ? sA : ca;
        pu.w[1] = hi ? sB : cb;
        pu.w[2] = hi ? cc : sA;
        pu.w[3] = hi ? cd : sB;
        short8 b0 = *(const short8*)&Vc[l32 * 64 + SWZ_RD(ks * 2 + hi, l32)];
        short8 b1 = *(const short8*)&Vc[(32 + l32) * 64 + SWZ_RD(ks * 2 + hi, l32)];
        O0 = MFMA32(pu.s, b0, O0);
        O1 = MFMA32(pu.s, b1, O1);
      }
    }

    if (kt < ktmax) {
      __syncthreads();   // publishes staged buffer + protects current one
      cur ^= 1;
    }
  }

  // Epilogue: row sum = own half + partner half; rescale + scalar stores.
  float lt = l_ + __shfl_xor(l_, 32);
  float inv = 1.0f / lt;
#pragma unroll
  for (int r = 0; r < 16; r++) {
    int crow = (r & 3) + 8 * (r >> 2) + 4 * hi;   // q-row within wave's 32
    float ivr = __shfl(inv, crow);                 // lane 'crow' holds that row
    unsigned short* dst =
        o + ((size_t)(b * SEQ + qbw + crow)) * DM + h * HS + l32;
    dst[0] = f2bf_fast(O0[r] * ivr);
    dst[32] = f2bf_fast(O1[r] * ivr);
  }
}

// ---------- G3: output projection, 128x64 tiles, XCD-sliced bm ----------
// Same remap as qkv: xcd owns bm slice (A 1 MB L2-resident); was 192 MB of
// cross-XCD panel re-reads at ~5 TB/s ≈ its whole runtime.
__global__ __launch_bounds__(256, 3) void out_gemm64(
    const unsigned short* __restrict__ A,    // [4096][1024] bf16
    const unsigned short* __restrict__ Bt,   // Wot [n][k]
    const float* __restrict__ bo,
    float* __restrict__ out) {
  __shared__ __align__(16) short As[128 * 64];
  __shared__ __align__(16) short Bs[64 * 64];
  const int tid = threadIdx.x;
  const int lid = (int)blockIdx.x;          // 0..511
  const int xcd = lid & 7, u = lid >> 3;    // u: 0..63
  const int bm = xcd * 4 + (u & 3);
  const int bn = u >> 2;                    // 0..15
  const int lane = tid & 63, wave = tid >> 6;
  const int quad = lane >> 4, l16 = lane & 15;
  const int wr = wave >> 1, wc = wave & 1;
  const int l7 = l16 & 7;
  const floatx4 fzero = {0.f, 0.f, 0.f, 0.f};

  floatx4 acc[4][2];
#pragma unroll
  for (int i = 0; i < 4; i++)
#pragma unroll
    for (int j = 0; j < 2; j++) acc[i][j] = fzero;

  const int srow = tid >> 3;
  const int scolw = SWZ_SRC(tid);
  const unsigned short* Ag = A + (size_t)(bm * 128 + srow) * DM + scolw;
  const unsigned short* Bg = Bt + (size_t)(bn * 64 + srow) * DM + scolw;
  short* Ad = As + tid * 8;
  short* Bd = Bs + tid * 8;

  for (int k0 = 0; k0 < DM; k0 += 64) {
    __syncthreads();
#pragma unroll
    for (int i = 0; i < 4; i++) g2l(Ag + (size_t)i * 32 * DM + k0, Ad + i * 2048);
#pragma unroll
    for (int i = 0; i < 2; i++) g2l(Bg + (size_t)i * 32 * DM + k0, Bd + i * 2048);
    __syncthreads();

    short8 af[4][2], bf[2][2];
#pragma unroll
    for (int ti = 0; ti < 4; ti++)
#pragma unroll
      for (int kh = 0; kh < 2; kh++)
        af[ti][kh] = *(const short8*)&As[(wr * 64 + ti * 16 + l16) * 64 +
                                          SWZ_RD(kh * 4 + quad, l7)];
#pragma unroll
    for (int tj = 0; tj < 2; tj++)
#pragma unroll
      for (int kh = 0; kh < 2; kh++)
        bf[tj][kh] = *(const short8*)&Bs[(wc * 32 + tj * 16 + l16) * 64 +
                                          SWZ_RD(kh * 4 + quad, l7)];
#pragma unroll
    for (int ti = 0; ti < 4; ti++)
#pragma unroll
      for (int tj = 0; tj < 2; tj++) {
        acc[ti][tj] = MFMA(af[ti][0], bf[tj][0], acc[ti][tj]);
        acc[ti][tj] = MFMA(af[ti][1], bf[tj][1], acc[ti][tj]);
      }
  }

#pragma unroll
  for (int ti = 0; ti < 4; ti++)
#pragma unroll
    for (int tj = 0; tj < 2; tj++) {
      int n = bn * 64 + wc * 32 + tj * 16 + l16;
      float bias = bo[n];
#pragma unroll
      for (int r = 0; r < 4; r++) {
        int m = bm * 128 + wr * 64 + ti * 16 + quad * 4 + r;
        out[(size_t)m * DM + n] = acc[ti][tj][r] + bias;
      }
    }
}

extern "C" void kernel_launch(void* const* d_in, const int* in_sizes, int n_in,
                              void* d_out, int out_size, void* d_ws, size_t ws_size,
                              hipStream_t stream) {
  const float* x  = (const float*)d_in[0];
  const float* Wq = (const float*)d_in[1];
  const float* Wk = (const float*)d_in[2];
  const float* Wv = (const float*)d_in[3];
  const float* Wo = (const float*)d_in[4];
  const float* bo = (const float*)d_in[5];
  float* out = (float*)d_out;

  const size_t nx = (size_t)NB * SEQ * DM;          // 4M
  const size_t nw = (size_t)DM * DM;                // 1M
  unsigned short* xb  = (unsigned short*)d_ws;
  unsigned short* wtq = xb + nx;                    // wtq|wtk|wtv contiguous
  unsigned short* wtk = wtq + nw;
  unsigned short* wtv = wtk + nw;
  unsigned short* wot = wtv + nw;
  unsigned short* qws = wot + nw;
  unsigned short* kws = qws + nx;
  unsigned short* vws = kws + nx;
  unsigned short* aws = vws + nx;

  prep_all<<<dim3(256, 5), dim3(256), 0, stream>>>(x, Wq, Wk, Wv, Wo,
                                                   xb, wtq, wtk, wtv, wot);
  qkv_gemm128<<<dim3(768), dim3(256), 0, stream>>>(xb, wtq, qws, kws, vws);
  attn_kernel<<<dim3(512), dim3(256), 0, stream>>>(qws, kws, vws, aws);
  out_gemm64<<<dim3(512), dim3(256), 0, stream>>>(aws, wot, bo, out);
}